// Round 6
// baseline (896.063 us; speedup 1.0000x reference)
//
#include <hip/hip_runtime.h>
#include <hip/hip_bf16.h>

typedef __bf16 bf16;
typedef bf16 bf16x8 __attribute__((ext_vector_type(8)));
typedef float f32x4 __attribute__((ext_vector_type(4)));

#define BSZ 8
#define NQ 900
#define NH 8
#define SUMHW 21504
#define NROW 7200

// NaN-guard bound: representable in bf16 (bf16 max ~3.39e38). fmaxf/fminf
// return the non-NaN operand, so NaN -> -BIGF. Real data is never near this,
// so the guard is mathematically neutral on the reference domain.
#define BIGF 3.3e38f

// ---------- runtime-dtype scalar load ----------
__device__ inline float ld_rt(const void* p, size_t i, int f32) {
  return f32 ? ((const float*)p)[i] : (float)((const bf16*)p)[i];
}

// ---------- runtime-dtype A-fragment load: 8 k-elems -> bf16x8 ----------
__device__ inline bf16x8 load_a8(const void* p, size_t i, int f32) {
  if (f32) {
    const float4* s = (const float4*)((const float*)p + i);
    float4 v0 = s[0], v1 = s[1];
    bf16x8 d;
    d[0] = (bf16)v0.x; d[1] = (bf16)v0.y; d[2] = (bf16)v0.z; d[3] = (bf16)v0.w;
    d[4] = (bf16)v1.x; d[5] = (bf16)v1.y; d[6] = (bf16)v1.z; d[7] = (bf16)v1.w;
    return d;
  }
  return *(const bf16x8*)((const bf16*)p + i);
}

// ---------------- dtype probe: flags[0]=is_f32, flags[1]=0, flags[2]=0 -------
// f32 data read as bf16 has ~46% of the interleaved mantissa-halves decoding to
// |x|>1000 (random exponent bits); genuine bf16 tensors have none. Threshold 32
// of 512 is >10 sigma from both sides -> deterministic across calls.
__global__ void probe_flags(const bf16* q, int* flags) {
  const int lane = threadIdx.x;
  int c = 0;
  for (int i = lane; i < 512; i += 64) {
    float x = (float)q[i];
    if (!(fabsf(x) <= 1000.f)) c++;  // counts NaN too
  }
#pragma unroll
  for (int m = 1; m < 64; m <<= 1) c += __shfl_xor(c, m, 64);
  if (lane == 0) {
    flags[0] = (c > 32) ? 1 : 0;
    flags[1] = 0;
    flags[2] = 0;
  }
}

// ------------- 256x256 transpose -> bf16 (Wt[n][k] = W[k][n]) -------------
__global__ __launch_bounds__(256) void transpose256(const void* __restrict__ in,
                                                    bf16* __restrict__ out,
                                                    const int* __restrict__ flags) {
  const int f32 = flags[0];
  int idx = blockIdx.x * 256 + threadIdx.x;
  int k = idx >> 8, n = idx & 255;
  out[n * 256 + k] = (bf16)ld_rt(in, idx, f32);
}

// ---- fused transpose of W_off(256x192)+W_attn(256x96) -> Wt_oa[288][256] ----
__global__ __launch_bounds__(256) void transpose_oa(const void* __restrict__ Woff,
                                                    const void* __restrict__ Wattn,
                                                    bf16* __restrict__ Wt,
                                                    const int* __restrict__ flags) {
  const int f32 = flags[0];
  int idx = blockIdx.x * 256 + threadIdx.x;  // 0..73727
  int n = idx >> 8, k = idx & 255;
  float v = (n < 192) ? ld_rt(Woff, (size_t)k * 192 + n, f32)
                      : ld_rt(Wattn, (size_t)k * 96 + (n - 192), f32);
  Wt[idx] = (bf16)v;
}

// ---------------- LDS-B GEMM: C[.,256] = A[.,256] @ Wt[256,256]^T + bias ----
// Wt (128 KB) staged into LDS once per block; barrier-free grid-stride loop
// over 128-row supertiles (8 waves x 16 rows). XOR swizzle e^=(row&7)*8 on
// write AND read (16-way conflict without it).
// R5 lesson: __launch_bounds__(512,2) capped VGPR at 128 -> acc+a spilled to
// scratch (+494 MB FETCH, +194 MB WRITE). LDS already caps us at 1 block/CU,
// so demand nothing: launch_bounds(512) -> ~190 regs live, no spill. Manual
// 1-tile A-prefetch (a/an dbuf) hides the ~900cyc HBM A-load under the
// current tile's MFMA chain (only 2 waves/SIMD resident -> ILP must hide it).
// Fragment mapping identical to the verified kernel:
//   A: lane(ml,qd) -> row tileM+ml, k = ks*32 + qd*8 + j
//   B: lane(ml,qd) -> col tn*16+ml, same k
//   C/D: col = tn*16+ml, row = tileM + qd*4 + rr
template <typename TC>
__global__ __launch_bounds__(512) void gemm_ldsb(
    const void* __restrict__ A, const bf16* __restrict__ Wt,
    const void* __restrict__ bias, TC* __restrict__ C, int rowbase, int M,
    const int* __restrict__ aflags, const int* __restrict__ bflags) {
  extern __shared__ bf16 Bs[];  // [256][256] xor-swizzled = 128 KB
  const int af32 = aflags[0], bf32 = bflags[0];
  const int t = threadIdx.x;
  const int w = t >> 6, lane = t & 63;
  const int ml = lane & 15, qd = lane >> 4;

  // ---- stage Wt -> LDS (one-time; reg-staged so both sides see the swizzle) --
#pragma unroll
  for (int i = 0; i < 16; ++i) {
    int g = t * 16 + i;  // granule = 8 bf16
    int row = g >> 5, e = (g & 31) * 8;
    bf16x8 v = *(const bf16x8*)(Wt + row * 256 + e);
    *(bf16x8*)&Bs[row * 256 + (e ^ ((row & 7) * 8))] = v;
  }
  __syncthreads();  // only barrier in the kernel; Bs is read-only after

  const int nst = (M + 127) >> 7;
  int st = blockIdx.x;
  if (st >= nst) return;

  auto aaddr = [&](int s) -> size_t {
    int r0 = s * 128 + w * 16 + ml;
    if (r0 > M - 1) r0 = M - 1;  // tail clamp (stores are guarded)
    return ((size_t)rowbase + r0) * 256;
  };

  bf16x8 a[8];
  {
    const size_t ar = aaddr(st);
#pragma unroll
    for (int ks = 0; ks < 8; ++ks) a[ks] = load_a8(A, ar + ks * 32 + qd * 8, af32);
  }

  for (; st < nst; st += gridDim.x) {
    const int stn = st + gridDim.x;
    bf16x8 an[8];
    if (stn < nst) {  // block-uniform branch
      const size_t ar = aaddr(stn);
#pragma unroll
      for (int ks = 0; ks < 8; ++ks) an[ks] = load_a8(A, ar + ks * 32 + qd * 8, af32);
    }

    f32x4 acc[16] = {};
#pragma unroll
    for (int ks = 0; ks < 8; ++ks) {
      const int swz = (ks * 32 + qd * 8) ^ ((ml & 7) * 8);
#pragma unroll
      for (int tn = 0; tn < 16; ++tn) {
        bf16x8 bb = *(const bf16x8*)&Bs[(tn * 16 + ml) * 256 + swz];
        acc[tn] = __builtin_amdgcn_mfma_f32_16x16x32_bf16(a[ks], bb, acc[tn], 0, 0, 0);
      }
    }

    const int tileM = st * 128 + w * 16;
#pragma unroll
    for (int tn = 0; tn < 16; ++tn) {
      int col = tn * 16 + ml;
      float bv = ld_rt(bias, col, bf32);
#pragma unroll
      for (int rr = 0; rr < 4; ++rr) {
        int row = tileM + qd * 4 + rr;
        float v = fminf(fmaxf(acc[tn][rr] + bv, -BIGF), BIGF);  // NaN-guard only
        if (row < M) C[((size_t)rowbase + row) * 256 + col] = (TC)v;
      }
    }

#pragma unroll
    for (int ks = 0; ks < 8; ++ks) a[ks] = an[ks];
  }
}

// ------ offsets+logits projection, LDS-B variant: B = Wt_oa[288][256] -------
__global__ __launch_bounds__(512) void gemm_oa_ldsb(
    const void* __restrict__ query, const bf16* __restrict__ Wt,
    const void* __restrict__ boff, const void* __restrict__ battn,
    float* __restrict__ offs, float* __restrict__ logits,
    const int* __restrict__ flags) {
  extern __shared__ bf16 Bs[];  // [288][256] xor-swizzled = 144 KB
  const int f32 = flags[0];
  const int t = threadIdx.x;
  const int w = t >> 6, lane = t & 63;
  const int ml = lane & 15, qd = lane >> 4;

#pragma unroll
  for (int i = 0; i < 18; ++i) {
    int g = t * 18 + i;  // 512*18 = 9216 granules = 288 rows
    int row = g >> 5, e = (g & 31) * 8;
    bf16x8 v = *(const bf16x8*)(Wt + row * 256 + e);
    *(bf16x8*)&Bs[row * 256 + (e ^ ((row & 7) * 8))] = v;
  }
  __syncthreads();

  const int nst = (NROW + 127) >> 7;
  for (int st = blockIdx.x; st < nst; st += gridDim.x) {
    const int tileM = st * 128 + w * 16;
    int r0 = tileM + ml;
    if (r0 > NROW - 1) r0 = NROW - 1;
    const size_t ar = (size_t)r0 * 256;

    bf16x8 a[8];
#pragma unroll
    for (int ks = 0; ks < 8; ++ks) a[ks] = load_a8(query, ar + ks * 32 + qd * 8, f32);

    f32x4 acc[18] = {};
#pragma unroll
    for (int ks = 0; ks < 8; ++ks) {
      const int swz = (ks * 32 + qd * 8) ^ ((ml & 7) * 8);
#pragma unroll
      for (int tn = 0; tn < 18; ++tn) {
        bf16x8 bb = *(const bf16x8*)&Bs[(tn * 16 + ml) * 256 + swz];
        acc[tn] = __builtin_amdgcn_mfma_f32_16x16x32_bf16(a[ks], bb, acc[tn], 0, 0, 0);
      }
    }

#pragma unroll
    for (int tn = 0; tn < 18; ++tn) {
      int col = tn * 16 + ml;
#pragma unroll
      for (int rr = 0; rr < 4; ++rr) {
        int row = tileM + qd * 4 + rr;
        if (row < NROW) {
          float v = acc[tn][rr];
          if (col < 192)
            offs[(size_t)row * 192 + col] = v + ld_rt(boff, col, f32);
          else
            logits[(size_t)row * 96 + (col - 192)] = v + ld_rt(battn, col - 192, f32);
        }
      }
    }
  }
}

// ------ softmax + bilinear sampling + weighted accumulate ------
__global__ __launch_bounds__(256) void msda_sample(
    const bf16* __restrict__ value, const void* __restrict__ refp,
    const float* __restrict__ offs, const float* __restrict__ logits,
    bf16* __restrict__ accb, int b_base, size_t batch_stride,
    const int* __restrict__ flags) {
  const int f32 = flags[0];
  const int qi = blockIdx.x, bl = blockIdx.y;
  const int b = b_base + bl;
  const int row = b * NQ + qi;
  const int t = threadIdx.x, h = t >> 5, d = t & 31;
  const bf16* valb = value + (size_t)bl * batch_stride;

  const float* lg = logits + (size_t)(row * NH + h) * 12;
  float lv[12];
#pragma unroll
  for (int i = 0; i < 12; ++i) lv[i] = fminf(fmaxf(lg[i], -BIGF), BIGF);  // NaN-guard
  float mx = -BIGF;
#pragma unroll
  for (int i = 0; i < 12; ++i) mx = fmaxf(mx, lv[i]);
  float e[12], se = 0.f;
#pragma unroll
  for (int i = 0; i < 12; ++i) {
    e[i] = __expf(lv[i] - mx);  // lv-mx <= 0: no overflow possible
    se += e[i];
  }
  const float inv = 1.f / se;

  const float* of = offs + (size_t)(row * NH + h) * 24;
  const int Hs[3] = {128, 64, 32}, Wd[3] = {128, 64, 32}, st[3] = {0, 16384, 20480};
  float acc = 0.f;
#pragma unroll
  for (int l = 0; l < 3; ++l) {
    const int Hl = Hs[l], Wl = Wd[l];
    float rx = ld_rt(refp, (size_t)(row * 3 + l) * 2 + 0, f32);
    float ry = ld_rt(refp, (size_t)(row * 3 + l) * 2 + 1, f32);
    const bf16* base = valb + (size_t)st[l] * 256 + h * 32 + d;
#pragma unroll
    for (int p = 0; p < 4; ++p) {
      float ox = of[(l * 4 + p) * 2 + 0], oy = of[(l * 4 + p) * 2 + 1];
      float px = (rx + ox / (float)Wl) * (float)Wl - 0.5f;
      float py = (ry + oy / (float)Hl) * (float)Hl - 0.5f;
      // int-cast safety clamp. Any |px| > Wl makes all corners invalid
      // (contribution 0) both here and in the reference, so clamping at
      // 1e6 >> Wl is exactly neutral. NaN -> -1e6 -> invalid -> 0.
      px = fminf(fmaxf(px, -1e6f), 1e6f);
      py = fminf(fmaxf(py, -1e6f), 1e6f);
      const float x0f = floorf(px), y0f = floorf(py);
      const float lx = px - x0f, ly = py - y0f;
      const int x0 = (int)x0f, y0 = (int)y0f;
      const float wgt = e[l * 4 + p] * inv;
      float s = 0.f;
#pragma unroll
      for (int cy = 0; cy < 2; ++cy) {
        const int iy = y0 + cy;
        const float wy = cy ? ly : 1.f - ly;
        const bool vy = (iy >= 0) && (iy < Hl);
        const int iyc = iy < 0 ? 0 : (iy > Hl - 1 ? Hl - 1 : iy);
#pragma unroll
        for (int cx = 0; cx < 2; ++cx) {
          const int ix = x0 + cx;
          const float wx = cx ? lx : 1.f - lx;
          const bool vx = (ix >= 0) && (ix < Wl);
          const int ixc = ix < 0 ? 0 : (ix > Wl - 1 ? Wl - 1 : ix);
          float g = (float)base[(size_t)(iyc * Wl + ixc) * 256];
          g = fminf(fmaxf(g, -BIGF), BIGF);  // NaN-guard only
          s += (vx && vy) ? wx * wy * g : 0.f;
        }
      }
      acc += wgt * s;
    }
  }
  accb[(size_t)row * 256 + t] = (bf16)acc;
}

extern "C" void kernel_launch(void* const* d_in, const int* in_sizes, int n_in,
                              void* d_out, int out_size, void* d_ws, size_t ws_size,
                              hipStream_t stream) {
  // dict order (harness-guaranteed)
  const void* query = d_in[0];
  const void* refp = d_in[1];
  const void* inpf = d_in[2];
  const void* W_off = d_in[5];
  const void* b_off = d_in[6];
  const void* W_attn = d_in[7];
  const void* b_attn = d_in[8];
  const void* W_val = d_in[9];
  const void* b_val = d_in[10];
  const void* W_out = d_in[11];
  const void* b_out = d_in[12];

  float* out = (float*)d_out;  // reference output dtype = float32
  char* ws = (char*)d_ws;
  int* flags = (int*)ws;
  const int* bf16flag = flags + 2;         // always 0
  bf16* Wt_val = (bf16*)(ws + 256);        // 131072 B
  bf16* Wt_out = (bf16*)(ws + 131328);     // 131072 B
  bf16* Wt_oa = (bf16*)(ws + 262400);      // 147456 B
  float* offs = (float*)(ws + 409856);     // 5529600 B
  float* logits = (float*)(ws + 5939456);  // 2764800 B
  bf16* accb = (bf16*)(ws + 8704256);      // 3686400 B
  bf16* value = (bf16*)(ws + 12390656);    // chunk 11010048 | full 88080384
  const unsigned long long WS_FULL = 12390656ULL + 88080384ULL;
  const unsigned long long WS_TIGHT = 12390656ULL + 11010048ULL;

  const int pipeline_ok = ws_size >= WS_TIGHT;
  const int full = ws_size >= WS_FULL;

  probe_flags<<<1, 64, 0, stream>>>((const bf16*)query, flags);
  if (pipeline_ok) {
    transpose256<<<256, 256, 0, stream>>>(W_val, Wt_val, flags);
    transpose256<<<256, 256, 0, stream>>>(W_out, Wt_out, flags);
    transpose_oa<<<288, 256, 0, stream>>>(W_off, W_attn, Wt_oa, flags);
    gemm_oa_ldsb<<<(NROW + 127) / 128, 512, 147456, stream>>>(
        query, Wt_oa, b_off, b_attn, offs, logits, flags);
    if (full) {
      gemm_ldsb<bf16><<<256, 512, 131072, stream>>>(
          inpf, Wt_val, b_val, value, 0, BSZ * SUMHW, flags, flags);
      msda_sample<<<dim3(NQ, BSZ), 256, 0, stream>>>(
          value, refp, offs, logits, accb, 0, (size_t)SUMHW * 256, flags);
    } else {
      for (int b = 0; b < BSZ; ++b) {
        gemm_ldsb<bf16><<<SUMHW / 128, 512, 131072, stream>>>(
            inpf, Wt_val, b_val, value - (size_t)b * SUMHW * 256, b * SUMHW, SUMHW,
            flags, flags);
        msda_sample<<<dim3(NQ, 1), 256, 0, stream>>>(value, refp, offs, logits, accb,
                                                     b, 0, flags);
      }
    }
    gemm_ldsb<float><<<(NROW + 127) / 128, 512, 131072, stream>>>(
        accb, Wt_out, b_out, out, 0, NROW, bf16flag, flags);
  }
}

// Round 7
// 875.367 us; speedup vs baseline: 1.0236x; 1.0236x over previous
//
#include <hip/hip_runtime.h>
#include <hip/hip_bf16.h>

typedef __bf16 bf16;
typedef bf16 bf16x8 __attribute__((ext_vector_type(8)));
typedef float f32x4 __attribute__((ext_vector_type(4)));

#define BSZ 8
#define NQ 900
#define NH 8
#define SUMHW 21504
#define NROW 7200

// NaN-guard bound: representable in bf16 (bf16 max ~3.39e38). fmaxf/fminf
// return the non-NaN operand, so NaN -> -BIGF. Real data is never near this,
// so the guard is mathematically neutral on the reference domain.
#define BIGF 3.3e38f

// ---------- runtime-dtype scalar load ----------
__device__ inline float ld_rt(const void* p, size_t i, int f32) {
  return f32 ? ((const float*)p)[i] : (float)((const bf16*)p)[i];
}

// ---------- runtime-dtype A-fragment load: 8 k-elems -> bf16x8 ----------
__device__ inline bf16x8 load_a8(const void* p, size_t i, int f32) {
  if (f32) {
    const float4* s = (const float4*)((const float*)p + i);
    float4 v0 = s[0], v1 = s[1];
    bf16x8 d;
    d[0] = (bf16)v0.x; d[1] = (bf16)v0.y; d[2] = (bf16)v0.z; d[3] = (bf16)v0.w;
    d[4] = (bf16)v1.x; d[5] = (bf16)v1.y; d[6] = (bf16)v1.z; d[7] = (bf16)v1.w;
    return d;
  }
  return *(const bf16x8*)((const bf16*)p + i);
}

// ---------------- dtype probe: flags[0]=is_f32, flags[1]=0, flags[2]=0 -------
// f32 data read as bf16 has ~46% of the interleaved mantissa-halves decoding to
// |x|>1000 (random exponent bits); genuine bf16 tensors have none. Threshold 32
// of 512 is >10 sigma from both sides -> deterministic across calls.
__global__ void probe_flags(const bf16* q, int* flags) {
  const int lane = threadIdx.x;
  int c = 0;
  for (int i = lane; i < 512; i += 64) {
    float x = (float)q[i];
    if (!(fabsf(x) <= 1000.f)) c++;  // counts NaN too
  }
#pragma unroll
  for (int m = 1; m < 64; m <<= 1) c += __shfl_xor(c, m, 64);
  if (lane == 0) {
    flags[0] = (c > 32) ? 1 : 0;
    flags[1] = 0;
    flags[2] = 0;
  }
}

// ------------- 256x256 transpose -> bf16 (Wt[n][k] = W[k][n]) -------------
__global__ __launch_bounds__(256) void transpose256(const void* __restrict__ in,
                                                    bf16* __restrict__ out,
                                                    const int* __restrict__ flags) {
  const int f32 = flags[0];
  int idx = blockIdx.x * 256 + threadIdx.x;
  int k = idx >> 8, n = idx & 255;
  out[n * 256 + k] = (bf16)ld_rt(in, idx, f32);
}

// ---- fused transpose of W_off(256x192)+W_attn(256x96) -> Wt_oa[288][256] ----
__global__ __launch_bounds__(256) void transpose_oa(const void* __restrict__ Woff,
                                                    const void* __restrict__ Wattn,
                                                    bf16* __restrict__ Wt,
                                                    const int* __restrict__ flags) {
  const int f32 = flags[0];
  int idx = blockIdx.x * 256 + threadIdx.x;  // 0..73727
  int n = idx >> 8, k = idx & 255;
  float v = (n < 192) ? ld_rt(Woff, (size_t)k * 192 + n, f32)
                      : ld_rt(Wattn, (size_t)k * 96 + (n - 192), f32);
  Wt[idx] = (bf16)v;
}

// ---------------- LDS-B GEMM: C[.,256] = A[.,256] @ Wt[256,256]^T + bias ----
// Wt (128 KB) staged into LDS once per block; barrier-free grid-stride loop
// over 128-row supertiles (8 waves x 16 rows). XOR swizzle e^=(row&7)*8 on
// write AND read (16-way conflict without it).
// R5/R6 lesson: VGPR_Count pinned at 128 both rounds -> the backend's DEFAULT
// occupancy target is 4 waves/EU (dynamic LDS hides the real 1-block/CU cap
// from the compiler), so ~190 live regs spilled to scratch (+500 MB HBM).
// __launch_bounds__(512, 1) declares min 1 wave/EU -> VGPR cap 512 -> no
// spill. Real occupancy is LDS-capped at 8 waves/CU either way.
// Manual 1-tile A-prefetch (a/an dbuf) hides the ~900cyc HBM A-load under the
// current tile's MFMA chain (only 2 waves/SIMD resident -> ILP must hide it).
// Fragment mapping identical to the verified kernel:
//   A: lane(ml,qd) -> row tileM+ml, k = ks*32 + qd*8 + j
//   B: lane(ml,qd) -> col tn*16+ml, same k
//   C/D: col = tn*16+ml, row = tileM + qd*4 + rr
template <typename TC>
__global__ __launch_bounds__(512, 1) void gemm_ldsb(
    const void* __restrict__ A, const bf16* __restrict__ Wt,
    const void* __restrict__ bias, TC* __restrict__ C, int rowbase, int M,
    const int* __restrict__ aflags, const int* __restrict__ bflags) {
  extern __shared__ bf16 Bs[];  // [256][256] xor-swizzled = 128 KB
  const int af32 = aflags[0], bf32 = bflags[0];
  const int t = threadIdx.x;
  const int w = t >> 6, lane = t & 63;
  const int ml = lane & 15, qd = lane >> 4;

  // ---- stage Wt -> LDS (one-time; reg-staged so both sides see the swizzle) --
#pragma unroll
  for (int i = 0; i < 16; ++i) {
    int g = t * 16 + i;  // granule = 8 bf16
    int row = g >> 5, e = (g & 31) * 8;
    bf16x8 v = *(const bf16x8*)(Wt + row * 256 + e);
    *(bf16x8*)&Bs[row * 256 + (e ^ ((row & 7) * 8))] = v;
  }
  __syncthreads();  // only barrier in the kernel; Bs is read-only after

  const int nst = (M + 127) >> 7;
  int st = blockIdx.x;
  if (st >= nst) return;

  auto aaddr = [&](int s) -> size_t {
    int r0 = s * 128 + w * 16 + ml;
    if (r0 > M - 1) r0 = M - 1;  // tail clamp (stores are guarded)
    return ((size_t)rowbase + r0) * 256;
  };

  bf16x8 a[8];
  {
    const size_t ar = aaddr(st);
#pragma unroll
    for (int ks = 0; ks < 8; ++ks) a[ks] = load_a8(A, ar + ks * 32 + qd * 8, af32);
  }

  for (; st < nst; st += gridDim.x) {
    const int stn = st + gridDim.x;
    bf16x8 an[8];
    if (stn < nst) {  // block-uniform branch
      const size_t ar = aaddr(stn);
#pragma unroll
      for (int ks = 0; ks < 8; ++ks) an[ks] = load_a8(A, ar + ks * 32 + qd * 8, af32);
    }

    f32x4 acc[16] = {};
#pragma unroll
    for (int ks = 0; ks < 8; ++ks) {
      const int swz = (ks * 32 + qd * 8) ^ ((ml & 7) * 8);
#pragma unroll
      for (int tn = 0; tn < 16; ++tn) {
        bf16x8 bb = *(const bf16x8*)&Bs[(tn * 16 + ml) * 256 + swz];
        acc[tn] = __builtin_amdgcn_mfma_f32_16x16x32_bf16(a[ks], bb, acc[tn], 0, 0, 0);
      }
    }

    const int tileM = st * 128 + w * 16;
#pragma unroll
    for (int tn = 0; tn < 16; ++tn) {
      int col = tn * 16 + ml;
      float bv = ld_rt(bias, col, bf32);
#pragma unroll
      for (int rr = 0; rr < 4; ++rr) {
        int row = tileM + qd * 4 + rr;
        float v = fminf(fmaxf(acc[tn][rr] + bv, -BIGF), BIGF);  // NaN-guard only
        if (row < M) C[((size_t)rowbase + row) * 256 + col] = (TC)v;
      }
    }

#pragma unroll
    for (int ks = 0; ks < 8; ++ks) a[ks] = an[ks];
  }
}

// ------ offsets+logits projection, LDS-B variant: B = Wt_oa[288][256] -------
__global__ __launch_bounds__(512, 1) void gemm_oa_ldsb(
    const void* __restrict__ query, const bf16* __restrict__ Wt,
    const void* __restrict__ boff, const void* __restrict__ battn,
    float* __restrict__ offs, float* __restrict__ logits,
    const int* __restrict__ flags) {
  extern __shared__ bf16 Bs[];  // [288][256] xor-swizzled = 144 KB
  const int f32 = flags[0];
  const int t = threadIdx.x;
  const int w = t >> 6, lane = t & 63;
  const int ml = lane & 15, qd = lane >> 4;

#pragma unroll
  for (int i = 0; i < 18; ++i) {
    int g = t * 18 + i;  // 512*18 = 9216 granules = 288 rows
    int row = g >> 5, e = (g & 31) * 8;
    bf16x8 v = *(const bf16x8*)(Wt + row * 256 + e);
    *(bf16x8*)&Bs[row * 256 + (e ^ ((row & 7) * 8))] = v;
  }
  __syncthreads();

  const int nst = (NROW + 127) >> 7;
  for (int st = blockIdx.x; st < nst; st += gridDim.x) {
    const int tileM = st * 128 + w * 16;
    int r0 = tileM + ml;
    if (r0 > NROW - 1) r0 = NROW - 1;
    const size_t ar = (size_t)r0 * 256;

    bf16x8 a[8];
#pragma unroll
    for (int ks = 0; ks < 8; ++ks) a[ks] = load_a8(query, ar + ks * 32 + qd * 8, f32);

    f32x4 acc[18] = {};
#pragma unroll
    for (int ks = 0; ks < 8; ++ks) {
      const int swz = (ks * 32 + qd * 8) ^ ((ml & 7) * 8);
#pragma unroll
      for (int tn = 0; tn < 18; ++tn) {
        bf16x8 bb = *(const bf16x8*)&Bs[(tn * 16 + ml) * 256 + swz];
        acc[tn] = __builtin_amdgcn_mfma_f32_16x16x32_bf16(a[ks], bb, acc[tn], 0, 0, 0);
      }
    }

#pragma unroll
    for (int tn = 0; tn < 18; ++tn) {
      int col = tn * 16 + ml;
#pragma unroll
      for (int rr = 0; rr < 4; ++rr) {
        int row = tileM + qd * 4 + rr;
        if (row < NROW) {
          float v = acc[tn][rr];
          if (col < 192)
            offs[(size_t)row * 192 + col] = v + ld_rt(boff, col, f32);
          else
            logits[(size_t)row * 96 + (col - 192)] = v + ld_rt(battn, col - 192, f32);
        }
      }
    }
  }
}

// ------ softmax + bilinear sampling + weighted accumulate ------
__global__ __launch_bounds__(256) void msda_sample(
    const bf16* __restrict__ value, const void* __restrict__ refp,
    const float* __restrict__ offs, const float* __restrict__ logits,
    bf16* __restrict__ accb, int b_base, size_t batch_stride,
    const int* __restrict__ flags) {
  const int f32 = flags[0];
  const int qi = blockIdx.x, bl = blockIdx.y;
  const int b = b_base + bl;
  const int row = b * NQ + qi;
  const int t = threadIdx.x, h = t >> 5, d = t & 31;
  const bf16* valb = value + (size_t)bl * batch_stride;

  const float* lg = logits + (size_t)(row * NH + h) * 12;
  float lv[12];
#pragma unroll
  for (int i = 0; i < 12; ++i) lv[i] = fminf(fmaxf(lg[i], -BIGF), BIGF);  // NaN-guard
  float mx = -BIGF;
#pragma unroll
  for (int i = 0; i < 12; ++i) mx = fmaxf(mx, lv[i]);
  float e[12], se = 0.f;
#pragma unroll
  for (int i = 0; i < 12; ++i) {
    e[i] = __expf(lv[i] - mx);  // lv-mx <= 0: no overflow possible
    se += e[i];
  }
  const float inv = 1.f / se;

  const float* of = offs + (size_t)(row * NH + h) * 24;
  const int Hs[3] = {128, 64, 32}, Wd[3] = {128, 64, 32}, st[3] = {0, 16384, 20480};
  float acc = 0.f;
#pragma unroll
  for (int l = 0; l < 3; ++l) {
    const int Hl = Hs[l], Wl = Wd[l];
    float rx = ld_rt(refp, (size_t)(row * 3 + l) * 2 + 0, f32);
    float ry = ld_rt(refp, (size_t)(row * 3 + l) * 2 + 1, f32);
    const bf16* base = valb + (size_t)st[l] * 256 + h * 32 + d;
#pragma unroll
    for (int p = 0; p < 4; ++p) {
      float ox = of[(l * 4 + p) * 2 + 0], oy = of[(l * 4 + p) * 2 + 1];
      float px = (rx + ox / (float)Wl) * (float)Wl - 0.5f;
      float py = (ry + oy / (float)Hl) * (float)Hl - 0.5f;
      // int-cast safety clamp. Any |px| > Wl makes all corners invalid
      // (contribution 0) both here and in the reference, so clamping at
      // 1e6 >> Wl is exactly neutral. NaN -> -1e6 -> invalid -> 0.
      px = fminf(fmaxf(px, -1e6f), 1e6f);
      py = fminf(fmaxf(py, -1e6f), 1e6f);
      const float x0f = floorf(px), y0f = floorf(py);
      const float lx = px - x0f, ly = py - y0f;
      const int x0 = (int)x0f, y0 = (int)y0f;
      const float wgt = e[l * 4 + p] * inv;
      float s = 0.f;
#pragma unroll
      for (int cy = 0; cy < 2; ++cy) {
        const int iy = y0 + cy;
        const float wy = cy ? ly : 1.f - ly;
        const bool vy = (iy >= 0) && (iy < Hl);
        const int iyc = iy < 0 ? 0 : (iy > Hl - 1 ? Hl - 1 : iy);
#pragma unroll
        for (int cx = 0; cx < 2; ++cx) {
          const int ix = x0 + cx;
          const float wx = cx ? lx : 1.f - lx;
          const bool vx = (ix >= 0) && (ix < Wl);
          const int ixc = ix < 0 ? 0 : (ix > Wl - 1 ? Wl - 1 : ix);
          float g = (float)base[(size_t)(iyc * Wl + ixc) * 256];
          g = fminf(fmaxf(g, -BIGF), BIGF);  // NaN-guard only
          s += (vx && vy) ? wx * wy * g : 0.f;
        }
      }
      acc += wgt * s;
    }
  }
  accb[(size_t)row * 256 + t] = (bf16)acc;
}

extern "C" void kernel_launch(void* const* d_in, const int* in_sizes, int n_in,
                              void* d_out, int out_size, void* d_ws, size_t ws_size,
                              hipStream_t stream) {
  // dict order (harness-guaranteed)
  const void* query = d_in[0];
  const void* refp = d_in[1];
  const void* inpf = d_in[2];
  const void* W_off = d_in[5];
  const void* b_off = d_in[6];
  const void* W_attn = d_in[7];
  const void* b_attn = d_in[8];
  const void* W_val = d_in[9];
  const void* b_val = d_in[10];
  const void* W_out = d_in[11];
  const void* b_out = d_in[12];

  float* out = (float*)d_out;  // reference output dtype = float32
  char* ws = (char*)d_ws;
  int* flags = (int*)ws;
  const int* bf16flag = flags + 2;         // always 0
  bf16* Wt_val = (bf16*)(ws + 256);        // 131072 B
  bf16* Wt_out = (bf16*)(ws + 131328);     // 131072 B
  bf16* Wt_oa = (bf16*)(ws + 262400);      // 147456 B
  float* offs = (float*)(ws + 409856);     // 5529600 B
  float* logits = (float*)(ws + 5939456);  // 2764800 B
  bf16* accb = (bf16*)(ws + 8704256);      // 3686400 B
  bf16* value = (bf16*)(ws + 12390656);    // chunk 11010048 | full 88080384
  const unsigned long long WS_FULL = 12390656ULL + 88080384ULL;
  const unsigned long long WS_TIGHT = 12390656ULL + 11010048ULL;

  const int pipeline_ok = ws_size >= WS_TIGHT;
  const int full = ws_size >= WS_FULL;

  probe_flags<<<1, 64, 0, stream>>>((const bf16*)query, flags);
  if (pipeline_ok) {
    transpose256<<<256, 256, 0, stream>>>(W_val, Wt_val, flags);
    transpose256<<<256, 256, 0, stream>>>(W_out, Wt_out, flags);
    transpose_oa<<<288, 256, 0, stream>>>(W_off, W_attn, Wt_oa, flags);
    gemm_oa_ldsb<<<(NROW + 127) / 128, 512, 147456, stream>>>(
        query, Wt_oa, b_off, b_attn, offs, logits, flags);
    if (full) {
      gemm_ldsb<bf16><<<256, 512, 131072, stream>>>(
          inpf, Wt_val, b_val, value, 0, BSZ * SUMHW, flags, flags);
      msda_sample<<<dim3(NQ, BSZ), 256, 0, stream>>>(
          value, refp, offs, logits, accb, 0, (size_t)SUMHW * 256, flags);
    } else {
      for (int b = 0; b < BSZ; ++b) {
        gemm_ldsb<bf16><<<SUMHW / 128, 512, 131072, stream>>>(
            inpf, Wt_val, b_val, value - (size_t)b * SUMHW * 256, b * SUMHW, SUMHW,
            flags, flags);
        msda_sample<<<dim3(NQ, 1), 256, 0, stream>>>(value, refp, offs, logits, accb,
                                                     b, 0, flags);
      }
    }
    gemm_ldsb<float><<<(NROW + 127) / 128, 512, 131072, stream>>>(
        accb, Wt_out, b_out, out, 0, NROW, bf16flag, flags);
  }
}

// Round 8
// 684.975 us; speedup vs baseline: 1.3082x; 1.2780x over previous
//
#include <hip/hip_runtime.h>
#include <hip/hip_bf16.h>

typedef __bf16 bf16;
typedef bf16 bf16x8 __attribute__((ext_vector_type(8)));
typedef float f32x4 __attribute__((ext_vector_type(4)));

#define BSZ 8
#define NQ 900
#define NH 8
#define SUMHW 21504
#define NROW 7200

// NaN-guard bound: representable in bf16 (bf16 max ~3.39e38). fmaxf/fminf
// return the non-NaN operand, so NaN -> -BIGF. Real data is never near this,
// so the guard is mathematically neutral on the reference domain.
#define BIGF 3.3e38f

// ---------- runtime-dtype scalar load ----------
__device__ inline float ld_rt(const void* p, size_t i, int f32) {
  return f32 ? ((const float*)p)[i] : (float)((const bf16*)p)[i];
}

// ---------- runtime-dtype A-fragment load: 8 k-elems -> bf16x8 ----------
__device__ inline bf16x8 load_a8(const void* p, size_t i, int f32) {
  if (f32) {
    const float4* s = (const float4*)((const float*)p + i);
    float4 v0 = s[0], v1 = s[1];
    bf16x8 d;
    d[0] = (bf16)v0.x; d[1] = (bf16)v0.y; d[2] = (bf16)v0.z; d[3] = (bf16)v0.w;
    d[4] = (bf16)v1.x; d[5] = (bf16)v1.y; d[6] = (bf16)v1.z; d[7] = (bf16)v1.w;
    return d;
  }
  return *(const bf16x8*)((const bf16*)p + i);
}

// ---------------- dtype probe: flags[0]=is_f32, flags[1]=0, flags[2]=0 -------
// f32 data read as bf16 has ~46% of the interleaved mantissa-halves decoding to
// |x|>1000 (random exponent bits); genuine bf16 tensors have none. Threshold 32
// of 512 is >10 sigma from both sides -> deterministic across calls.
__global__ void probe_flags(const bf16* q, int* flags) {
  const int lane = threadIdx.x;
  int c = 0;
  for (int i = lane; i < 512; i += 64) {
    float x = (float)q[i];
    if (!(fabsf(x) <= 1000.f)) c++;  // counts NaN too
  }
#pragma unroll
  for (int m = 1; m < 64; m <<= 1) c += __shfl_xor(c, m, 64);
  if (lane == 0) {
    flags[0] = (c > 32) ? 1 : 0;
    flags[1] = 0;
    flags[2] = 0;
  }
}

// ------------- 256x256 transpose -> bf16 (Wt[n][k] = W[k][n]) -------------
__global__ __launch_bounds__(256) void transpose256(const void* __restrict__ in,
                                                    bf16* __restrict__ out,
                                                    const int* __restrict__ flags) {
  const int f32 = flags[0];
  int idx = blockIdx.x * 256 + threadIdx.x;
  int k = idx >> 8, n = idx & 255;
  out[n * 256 + k] = (bf16)ld_rt(in, idx, f32);
}

// ---- fused transpose of W_off(256x192)+W_attn(256x96) -> Wt_oa[288][256] ----
__global__ __launch_bounds__(256) void transpose_oa(const void* __restrict__ Woff,
                                                    const void* __restrict__ Wattn,
                                                    bf16* __restrict__ Wt,
                                                    const int* __restrict__ flags) {
  const int f32 = flags[0];
  int idx = blockIdx.x * 256 + threadIdx.x;  // 0..73727
  int n = idx >> 8, k = idx & 255;
  float v = (n < 192) ? ld_rt(Woff, (size_t)k * 192 + n, f32)
                      : ld_rt(Wattn, (size_t)k * 96 + (n - 192), f32);
  Wt[idx] = (bf16)v;
}

// ---------------- LDS-B GEMM: C[.,256] = A[.,256] @ Wt[256,256]^T + bias ----
// Wt (128 KB) staged into LDS once per block; barrier-free grid-stride loop
// over 64-row supertiles (4 waves x 16 rows). XOR swizzle e^=(row&7)*8 on
// write AND read (16-way conflict without it).
// R5-R7 lesson: a 512-thread WG = 8 waves MUST co-reside on one CU -> 2
// waves/SIMD mandatory -> hard 256-reg/wave budget; compiler capped arch
// VGPRs at 128 and spilled ~60 regs (+500 MB scratch HBM traffic), and NO
// launch_bounds variant could change it (R6 == R7 counters byte-identical).
// 256-thread WG (4 waves) needs only 1 wave/SIMD -> allocator free to ~256+
// arch regs -> ~190-reg live set fits, zero spill. Occupancy stays 1 block/CU
// (LDS-capped) either way; spill traffic, not occupancy, was the binding
// constraint. A-prefetch (a/an dbuf) hides the HBM A-load under the 128-MFMA
// chain (1 wave/SIMD -> ILP must do all the hiding).
// Fragment mapping identical to the verified kernel:
//   A: lane(ml,qd) -> row tileM+ml, k = ks*32 + qd*8 + j
//   B: lane(ml,qd) -> col tn*16+ml, same k
//   C/D: col = tn*16+ml, row = tileM + qd*4 + rr
template <typename TC>
__global__ __launch_bounds__(256, 1) void gemm_ldsb(
    const void* __restrict__ A, const bf16* __restrict__ Wt,
    const void* __restrict__ bias, TC* __restrict__ C, int rowbase, int M,
    const int* __restrict__ aflags, const int* __restrict__ bflags) {
  extern __shared__ bf16 Bs[];  // [256][256] xor-swizzled = 128 KB
  const int af32 = aflags[0], bf32 = bflags[0];
  const int t = threadIdx.x;
  const int w = t >> 6, lane = t & 63;
  const int ml = lane & 15, qd = lane >> 4;

  // ---- stage Wt -> LDS (one-time; reg-staged so both sides see the swizzle) --
#pragma unroll
  for (int i = 0; i < 32; ++i) {
    int g = t * 32 + i;  // granule = 8 bf16; 256 thr x 32 = 8192 granules
    int row = g >> 5, e = (g & 31) * 8;
    bf16x8 v = *(const bf16x8*)(Wt + row * 256 + e);
    *(bf16x8*)&Bs[row * 256 + (e ^ ((row & 7) * 8))] = v;
  }
  __syncthreads();  // only barrier in the kernel; Bs is read-only after

  const int nst = (M + 63) >> 6;
  int st = blockIdx.x;
  if (st >= nst) return;

  auto aaddr = [&](int s) -> size_t {
    int r0 = s * 64 + w * 16 + ml;
    if (r0 > M - 1) r0 = M - 1;  // tail clamp (stores are guarded)
    return ((size_t)rowbase + r0) * 256;
  };

  bf16x8 a[8];
  {
    const size_t ar = aaddr(st);
#pragma unroll
    for (int ks = 0; ks < 8; ++ks) a[ks] = load_a8(A, ar + ks * 32 + qd * 8, af32);
  }

  for (; st < nst; st += gridDim.x) {
    const int stn = st + gridDim.x;
    bf16x8 an[8];
    if (stn < nst) {  // block-uniform branch
      const size_t ar = aaddr(stn);
#pragma unroll
      for (int ks = 0; ks < 8; ++ks) an[ks] = load_a8(A, ar + ks * 32 + qd * 8, af32);
    }

    f32x4 acc[16] = {};
#pragma unroll
    for (int ks = 0; ks < 8; ++ks) {
      const int swz = (ks * 32 + qd * 8) ^ ((ml & 7) * 8);
#pragma unroll
      for (int tn = 0; tn < 16; ++tn) {
        bf16x8 bb = *(const bf16x8*)&Bs[(tn * 16 + ml) * 256 + swz];
        acc[tn] = __builtin_amdgcn_mfma_f32_16x16x32_bf16(a[ks], bb, acc[tn], 0, 0, 0);
      }
    }

    const int tileM = st * 64 + w * 16;
#pragma unroll
    for (int tn = 0; tn < 16; ++tn) {
      int col = tn * 16 + ml;
      float bv = ld_rt(bias, col, bf32);
#pragma unroll
      for (int rr = 0; rr < 4; ++rr) {
        int row = tileM + qd * 4 + rr;
        float v = fminf(fmaxf(acc[tn][rr] + bv, -BIGF), BIGF);  // NaN-guard only
        if (row < M) C[((size_t)rowbase + row) * 256 + col] = (TC)v;
      }
    }

#pragma unroll
    for (int ks = 0; ks < 8; ++ks) a[ks] = an[ks];
  }
}

// ------ offsets+logits projection, LDS-B variant: B = Wt_oa[288][256] -------
__global__ __launch_bounds__(256, 1) void gemm_oa_ldsb(
    const void* __restrict__ query, const bf16* __restrict__ Wt,
    const void* __restrict__ boff, const void* __restrict__ battn,
    float* __restrict__ offs, float* __restrict__ logits,
    const int* __restrict__ flags) {
  extern __shared__ bf16 Bs[];  // [288][256] xor-swizzled = 144 KB
  const int f32 = flags[0];
  const int t = threadIdx.x;
  const int w = t >> 6, lane = t & 63;
  const int ml = lane & 15, qd = lane >> 4;

#pragma unroll
  for (int i = 0; i < 36; ++i) {
    int g = t * 36 + i;  // 256*36 = 9216 granules = 288 rows
    int row = g >> 5, e = (g & 31) * 8;
    bf16x8 v = *(const bf16x8*)(Wt + row * 256 + e);
    *(bf16x8*)&Bs[row * 256 + (e ^ ((row & 7) * 8))] = v;
  }
  __syncthreads();

  const int nst = (NROW + 63) >> 6;
  for (int st = blockIdx.x; st < nst; st += gridDim.x) {
    const int tileM = st * 64 + w * 16;
    int r0 = tileM + ml;
    if (r0 > NROW - 1) r0 = NROW - 1;
    const size_t ar = (size_t)r0 * 256;

    bf16x8 a[8];
#pragma unroll
    for (int ks = 0; ks < 8; ++ks) a[ks] = load_a8(query, ar + ks * 32 + qd * 8, f32);

    f32x4 acc[18] = {};
#pragma unroll
    for (int ks = 0; ks < 8; ++ks) {
      const int swz = (ks * 32 + qd * 8) ^ ((ml & 7) * 8);
#pragma unroll
      for (int tn = 0; tn < 18; ++tn) {
        bf16x8 bb = *(const bf16x8*)&Bs[(tn * 16 + ml) * 256 + swz];
        acc[tn] = __builtin_amdgcn_mfma_f32_16x16x32_bf16(a[ks], bb, acc[tn], 0, 0, 0);
      }
    }

#pragma unroll
    for (int tn = 0; tn < 18; ++tn) {
      int col = tn * 16 + ml;
#pragma unroll
      for (int rr = 0; rr < 4; ++rr) {
        int row = tileM + qd * 4 + rr;
        if (row < NROW) {
          float v = acc[tn][rr];
          if (col < 192)
            offs[(size_t)row * 192 + col] = v + ld_rt(boff, col, f32);
          else
            logits[(size_t)row * 96 + (col - 192)] = v + ld_rt(battn, col - 192, f32);
        }
      }
    }
  }
}

// ------ softmax + bilinear sampling + weighted accumulate ------
__global__ __launch_bounds__(256) void msda_sample(
    const bf16* __restrict__ value, const void* __restrict__ refp,
    const float* __restrict__ offs, const float* __restrict__ logits,
    bf16* __restrict__ accb, int b_base, size_t batch_stride,
    const int* __restrict__ flags) {
  const int f32 = flags[0];
  const int qi = blockIdx.x, bl = blockIdx.y;
  const int b = b_base + bl;
  const int row = b * NQ + qi;
  const int t = threadIdx.x, h = t >> 5, d = t & 31;
  const bf16* valb = value + (size_t)bl * batch_stride;

  const float* lg = logits + (size_t)(row * NH + h) * 12;
  float lv[12];
#pragma unroll
  for (int i = 0; i < 12; ++i) lv[i] = fminf(fmaxf(lg[i], -BIGF), BIGF);  // NaN-guard
  float mx = -BIGF;
#pragma unroll
  for (int i = 0; i < 12; ++i) mx = fmaxf(mx, lv[i]);
  float e[12], se = 0.f;
#pragma unroll
  for (int i = 0; i < 12; ++i) {
    e[i] = __expf(lv[i] - mx);  // lv-mx <= 0: no overflow possible
    se += e[i];
  }
  const float inv = 1.f / se;

  const float* of = offs + (size_t)(row * NH + h) * 24;
  const int Hs[3] = {128, 64, 32}, Wd[3] = {128, 64, 32}, st[3] = {0, 16384, 20480};
  float acc = 0.f;
#pragma unroll
  for (int l = 0; l < 3; ++l) {
    const int Hl = Hs[l], Wl = Wd[l];
    float rx = ld_rt(refp, (size_t)(row * 3 + l) * 2 + 0, f32);
    float ry = ld_rt(refp, (size_t)(row * 3 + l) * 2 + 1, f32);
    const bf16* base = valb + (size_t)st[l] * 256 + h * 32 + d;
#pragma unroll
    for (int p = 0; p < 4; ++p) {
      float ox = of[(l * 4 + p) * 2 + 0], oy = of[(l * 4 + p) * 2 + 1];
      float px = (rx + ox / (float)Wl) * (float)Wl - 0.5f;
      float py = (ry + oy / (float)Hl) * (float)Hl - 0.5f;
      // int-cast safety clamp. Any |px| > Wl makes all corners invalid
      // (contribution 0) both here and in the reference, so clamping at
      // 1e6 >> Wl is exactly neutral. NaN -> -1e6 -> invalid -> 0.
      px = fminf(fmaxf(px, -1e6f), 1e6f);
      py = fminf(fmaxf(py, -1e6f), 1e6f);
      const float x0f = floorf(px), y0f = floorf(py);
      const float lx = px - x0f, ly = py - y0f;
      const int x0 = (int)x0f, y0 = (int)y0f;
      const float wgt = e[l * 4 + p] * inv;
      float s = 0.f;
#pragma unroll
      for (int cy = 0; cy < 2; ++cy) {
        const int iy = y0 + cy;
        const float wy = cy ? ly : 1.f - ly;
        const bool vy = (iy >= 0) && (iy < Hl);
        const int iyc = iy < 0 ? 0 : (iy > Hl - 1 ? Hl - 1 : iy);
#pragma unroll
        for (int cx = 0; cx < 2; ++cx) {
          const int ix = x0 + cx;
          const float wx = cx ? lx : 1.f - lx;
          const bool vx = (ix >= 0) && (ix < Wl);
          const int ixc = ix < 0 ? 0 : (ix > Wl - 1 ? Wl - 1 : ix);
          float g = (float)base[(size_t)(iyc * Wl + ixc) * 256];
          g = fminf(fmaxf(g, -BIGF), BIGF);  // NaN-guard only
          s += (vx && vy) ? wx * wy * g : 0.f;
        }
      }
      acc += wgt * s;
    }
  }
  accb[(size_t)row * 256 + t] = (bf16)acc;
}

extern "C" void kernel_launch(void* const* d_in, const int* in_sizes, int n_in,
                              void* d_out, int out_size, void* d_ws, size_t ws_size,
                              hipStream_t stream) {
  // dict order (harness-guaranteed)
  const void* query = d_in[0];
  const void* refp = d_in[1];
  const void* inpf = d_in[2];
  const void* W_off = d_in[5];
  const void* b_off = d_in[6];
  const void* W_attn = d_in[7];
  const void* b_attn = d_in[8];
  const void* W_val = d_in[9];
  const void* b_val = d_in[10];
  const void* W_out = d_in[11];
  const void* b_out = d_in[12];

  float* out = (float*)d_out;  // reference output dtype = float32
  char* ws = (char*)d_ws;
  int* flags = (int*)ws;
  const int* bf16flag = flags + 2;         // always 0
  bf16* Wt_val = (bf16*)(ws + 256);        // 131072 B
  bf16* Wt_out = (bf16*)(ws + 131328);     // 131072 B
  bf16* Wt_oa = (bf16*)(ws + 262400);      // 147456 B
  float* offs = (float*)(ws + 409856);     // 5529600 B
  float* logits = (float*)(ws + 5939456);  // 2764800 B
  bf16* accb = (bf16*)(ws + 8704256);      // 3686400 B
  bf16* value = (bf16*)(ws + 12390656);    // chunk 11010048 | full 88080384
  const unsigned long long WS_FULL = 12390656ULL + 88080384ULL;
  const unsigned long long WS_TIGHT = 12390656ULL + 11010048ULL;

  const int pipeline_ok = ws_size >= WS_TIGHT;
  const int full = ws_size >= WS_FULL;

  probe_flags<<<1, 64, 0, stream>>>((const bf16*)query, flags);
  if (pipeline_ok) {
    transpose256<<<256, 256, 0, stream>>>(W_val, Wt_val, flags);
    transpose256<<<256, 256, 0, stream>>>(W_out, Wt_out, flags);
    transpose_oa<<<288, 256, 0, stream>>>(W_off, W_attn, Wt_oa, flags);
    gemm_oa_ldsb<<<(NROW + 63) / 64, 256, 147456, stream>>>(
        query, Wt_oa, b_off, b_attn, offs, logits, flags);
    if (full) {
      gemm_ldsb<bf16><<<256, 256, 131072, stream>>>(
          inpf, Wt_val, b_val, value, 0, BSZ * SUMHW, flags, flags);
      msda_sample<<<dim3(NQ, BSZ), 256, 0, stream>>>(
          value, refp, offs, logits, accb, 0, (size_t)SUMHW * 256, flags);
    } else {
      for (int b = 0; b < BSZ; ++b) {
        gemm_ldsb<bf16><<<256, 256, 131072, stream>>>(
            inpf, Wt_val, b_val, value - (size_t)b * SUMHW * 256, b * SUMHW, SUMHW,
            flags, flags);
        msda_sample<<<dim3(NQ, 1), 256, 0, stream>>>(value, refp, offs, logits, accb,
                                                     b, 0, flags);
      }
    }
    gemm_ldsb<float><<<(NROW + 63) / 64, 256, 131072, stream>>>(
        accb, Wt_out, b_out, out, 0, NROW, bf16flag, flags);
  }
}

// Round 10
// 466.759 us; speedup vs baseline: 1.9198x; 1.4675x over previous
//
#include <hip/hip_runtime.h>
#include <hip/hip_bf16.h>

typedef __bf16 bf16;
typedef bf16 bf16x8 __attribute__((ext_vector_type(8)));
typedef float f32x4 __attribute__((ext_vector_type(4)));

#define BSZ 8
#define NQ 900
#define NH 8
#define SUMHW 21504
#define NROW 7200

// NaN-guard bound: representable in bf16 (bf16 max ~3.39e38). fmaxf/fminf
// return the non-NaN operand, so NaN -> -BIGF. Real data is never near this,
// so the guard is mathematically neutral on the reference domain.
#define BIGF 3.3e38f

// ---------- runtime-dtype scalar load ----------
__device__ inline float ld_rt(const void* p, size_t i, int f32) {
  return f32 ? ((const float*)p)[i] : (float)((const bf16*)p)[i];
}

// ---------- runtime-dtype A-fragment load: 8 k-elems -> bf16x8 ----------
__device__ inline bf16x8 load_a8(const void* p, size_t i, int f32) {
  if (f32) {
    const float4* s = (const float4*)((const float*)p + i);
    float4 v0 = s[0], v1 = s[1];
    bf16x8 d;
    d[0] = (bf16)v0.x; d[1] = (bf16)v0.y; d[2] = (bf16)v0.z; d[3] = (bf16)v0.w;
    d[4] = (bf16)v1.x; d[5] = (bf16)v1.y; d[6] = (bf16)v1.z; d[7] = (bf16)v1.w;
    return d;
  }
  return *(const bf16x8*)((const bf16*)p + i);
}

// ---------------- dtype probe: flags[0]=is_f32, flags[1]=0, flags[2]=0 -------
// f32 data read as bf16 has ~46% of the interleaved mantissa-halves decoding to
// |x|>1000 (random exponent bits); genuine bf16 tensors have none. Threshold 32
// of 512 is >10 sigma from both sides -> deterministic across calls.
__global__ void probe_flags(const bf16* q, int* flags) {
  const int lane = threadIdx.x;
  int c = 0;
  for (int i = lane; i < 512; i += 64) {
    float x = (float)q[i];
    if (!(fabsf(x) <= 1000.f)) c++;  // counts NaN too
  }
#pragma unroll
  for (int m = 1; m < 64; m <<= 1) c += __shfl_xor(c, m, 64);
  if (lane == 0) {
    flags[0] = (c > 32) ? 1 : 0;
    flags[1] = 0;
    flags[2] = 0;
  }
}

// -------- W[256][256] -> frag-layout Wt --------
// Dest index for (col n, k): tn=n>>4, ml=n&15, ks=k>>5, qd=(k>>3)&3, j=k&7:
//   Wt[(((ks*16+tn)*64) + qd*16 + ml)*8 + j]
// so a wave's B-fragment load in the GEMM is Wt + ((ks*16+tn)*64 + lane)*8 --
// 64 lanes x 16 B fully contiguous (1 KB coalesced, 8 sequential lines)
// instead of 16 scattered 512B-strided lines (R4's ~100cyc/VMEM bottleneck).
__global__ __launch_bounds__(256) void transpose_frag(const void* __restrict__ in,
                                                      bf16* __restrict__ out,
                                                      const int* __restrict__ flags) {
  const int f32 = flags[0];
  int idx = blockIdx.x * 256 + threadIdx.x;  // over 65536: (k,n) of W[k][n]
  int k = idx >> 8, n = idx & 255;
  int tn = n >> 4, ml = n & 15;
  int ks = k >> 5, qd = (k >> 3) & 3, j = k & 7;
  out[(((ks * 16 + tn) * 64) + qd * 16 + ml) * 8 + j] = (bf16)ld_rt(in, idx, f32);
}

// ---- fused frag-transpose of W_off(256x192)+W_attn(256x96): 288 cols ----
__global__ __launch_bounds__(256) void transpose_oa_frag(
    const void* __restrict__ Woff, const void* __restrict__ Wattn,
    bf16* __restrict__ Wt, const int* __restrict__ flags) {
  const int f32 = flags[0];
  int idx = blockIdx.x * 256 + threadIdx.x;  // 0..73727: n = idx>>8, k = idx&255
  int n = idx >> 8, k = idx & 255;
  float v = (n < 192) ? ld_rt(Woff, (size_t)k * 192 + n, f32)
                      : ld_rt(Wattn, (size_t)k * 96 + (n - 192), f32);
  int tn = n >> 4, ml = n & 15;
  int ks = k >> 5, qd = (k >> 3) & 3, j = k & 7;
  Wt[(((ks * 18 + tn) * 64) + qd * 16 + ml) * 8 + j] = (bf16)v;
}

// ------- barrier-free streaming GEMM, frag-layout B: C = A @ W^T + bias ------
// R4 structure (best GEMM measured: FETCH/WRITE exactly ideal, occupancy 30%)
// with its one defect fixed: B-loads are now contiguous 1 KB wave transactions
// from the frag-layout Wt (L2-resident, replicated per XCD). No LDS, no
// barriers, 4-wave blocks, 16 rows/wave -> acc[16]=64 regs, total ~90 VGPR.
// Fragment mapping identical to the verified kernel:
//   A: lane(ml,qd) -> row blockM+ml, k = ks*32 + qd*8 + j
//   B: frag block (ks,tn), lane -> col tn*16+ml, same k
//   C/D: col = tn*16+ml, row = blockM + qd*4 + rr
template <typename TC>
__global__ __launch_bounds__(256) void gemm_sf(
    const void* __restrict__ A, const bf16* __restrict__ Wt,
    const void* __restrict__ bias, TC* __restrict__ C, int rowbase, int M,
    const int* __restrict__ aflags, const int* __restrict__ bflags) {
  const int af32 = aflags[0], bf32 = bflags[0];
  const int t = threadIdx.x;
  const int w = t >> 6, lane = t & 63;
  const int ml = lane & 15, qd = lane >> 4;
  const int blockM = blockIdx.x * 64 + w * 16;
  f32x4 acc[16] = {};

  int r0 = blockM + ml;
  if (r0 > M - 1) r0 = M - 1;  // tail clamp (stores are guarded)
  const size_t ar = ((size_t)rowbase + r0) * 256;
  const bf16* bp = Wt + lane * 8;

  for (int ks = 0; ks < 8; ++ks) {
    bf16x8 a = load_a8(A, ar + ks * 32 + qd * 8, af32);
    const bf16* bk = bp + (size_t)ks * 16 * 512;  // 512 bf16 per frag block
#pragma unroll
    for (int tn = 0; tn < 16; ++tn) {
      bf16x8 bb = *(const bf16x8*)(bk + tn * 512);
      acc[tn] = __builtin_amdgcn_mfma_f32_16x16x32_bf16(a, bb, acc[tn], 0, 0, 0);
    }
  }

#pragma unroll
  for (int tn = 0; tn < 16; ++tn) {
    int col = tn * 16 + ml;
    float bv = ld_rt(bias, col, bf32);
#pragma unroll
    for (int rr = 0; rr < 4; ++rr) {
      int row = blockM + qd * 4 + rr;
      float v = fminf(fmaxf(acc[tn][rr] + bv, -BIGF), BIGF);  // NaN-guard only
      if (row < M) C[((size_t)rowbase + row) * 256 + col] = (TC)v;
    }
  }
}

// ------ offsets+logits projection, frag-layout B: 288 cols (18 tn-blocks) ----
__global__ __launch_bounds__(256) void gemm_oa_sf(
    const void* __restrict__ query, const bf16* __restrict__ Wt,
    const void* __restrict__ boff, const void* __restrict__ battn,
    float* __restrict__ offs, float* __restrict__ logits,
    const int* __restrict__ flags) {
  const int f32 = flags[0];
  const int t = threadIdx.x;
  const int w = t >> 6, lane = t & 63;
  const int ml = lane & 15, qd = lane >> 4;
  const int blockM = blockIdx.x * 64 + w * 16;
  f32x4 acc[18] = {};

  int r0 = blockM + ml;
  if (r0 > NROW - 1) r0 = NROW - 1;
  const size_t ar = (size_t)r0 * 256;
  const bf16* bp = Wt + lane * 8;

  for (int ks = 0; ks < 8; ++ks) {
    bf16x8 a = load_a8(query, ar + ks * 32 + qd * 8, f32);
    const bf16* bk = bp + (size_t)ks * 18 * 512;
#pragma unroll
    for (int tn = 0; tn < 18; ++tn) {
      bf16x8 bb = *(const bf16x8*)(bk + tn * 512);
      acc[tn] = __builtin_amdgcn_mfma_f32_16x16x32_bf16(a, bb, acc[tn], 0, 0, 0);
    }
  }

#pragma unroll
  for (int tn = 0; tn < 18; ++tn) {
    int col = tn * 16 + ml;
#pragma unroll
    for (int rr = 0; rr < 4; ++rr) {
      int row = blockM + qd * 4 + rr;
      if (row < NROW) {
        float v = acc[tn][rr];
        if (col < 192)
          offs[(size_t)row * 192 + col] = v + ld_rt(boff, col, f32);
        else
          logits[(size_t)row * 96 + (col - 192)] = v + ld_rt(battn, col - 192, f32);
      }
    }
  }
}

// ------ softmax + bilinear sampling + weighted accumulate ------
__global__ __launch_bounds__(256) void msda_sample(
    const bf16* __restrict__ value, const void* __restrict__ refp,
    const float* __restrict__ offs, const float* __restrict__ logits,
    bf16* __restrict__ accb, int b_base, size_t batch_stride,
    const int* __restrict__ flags) {
  const int f32 = flags[0];
  const int qi = blockIdx.x, bl = blockIdx.y;
  const int b = b_base + bl;
  const int row = b * NQ + qi;
  const int t = threadIdx.x, h = t >> 5, d = t & 31;
  const bf16* valb = value + (size_t)bl * batch_stride;

  const float* lg = logits + (size_t)(row * NH + h) * 12;
  float lv[12];
#pragma unroll
  for (int i = 0; i < 12; ++i) lv[i] = fminf(fmaxf(lg[i], -BIGF), BIGF);  // NaN-guard
  float mx = -BIGF;
#pragma unroll
  for (int i = 0; i < 12; ++i) mx = fmaxf(mx, lv[i]);
  float e[12], se = 0.f;
#pragma unroll
  for (int i = 0; i < 12; ++i) {
    e[i] = __expf(lv[i] - mx);  // lv-mx <= 0: no overflow possible
    se += e[i];
  }
  const float inv = 1.f / se;

  const float* of = offs + (size_t)(row * NH + h) * 24;
  const int Hs[3] = {128, 64, 32}, Wd[3] = {128, 64, 32}, st[3] = {0, 16384, 20480};
  float acc = 0.f;
#pragma unroll
  for (int l = 0; l < 3; ++l) {
    const int Hl = Hs[l], Wl = Wd[l];
    float rx = ld_rt(refp, (size_t)(row * 3 + l) * 2 + 0, f32);
    float ry = ld_rt(refp, (size_t)(row * 3 + l) * 2 + 1, f32);
    const bf16* base = valb + (size_t)st[l] * 256 + h * 32 + d;
#pragma unroll
    for (int p = 0; p < 4; ++p) {
      float ox = of[(l * 4 + p) * 2 + 0], oy = of[(l * 4 + p) * 2 + 1];
      float px = (rx + ox / (float)Wl) * (float)Wl - 0.5f;
      float py = (ry + oy / (float)Hl) * (float)Hl - 0.5f;
      // int-cast safety clamp. Any |px| > Wl makes all corners invalid
      // (contribution 0) both here and in the reference, so clamping at
      // 1e6 >> Wl is exactly neutral. NaN -> -1e6 -> invalid -> 0.
      px = fminf(fmaxf(px, -1e6f), 1e6f);
      py = fminf(fmaxf(py, -1e6f), 1e6f);
      const float x0f = floorf(px), y0f = floorf(py);
      const float lx = px - x0f, ly = py - y0f;
      const int x0 = (int)x0f, y0 = (int)y0f;
      const float wgt = e[l * 4 + p] * inv;
      float s = 0.f;
#pragma unroll
      for (int cy = 0; cy < 2; ++cy) {
        const int iy = y0 + cy;
        const float wy = cy ? ly : 1.f - ly;
        const bool vy = (iy >= 0) && (iy < Hl);
        const int iyc = iy < 0 ? 0 : (iy > Hl - 1 ? Hl - 1 : iy);
#pragma unroll
        for (int cx = 0; cx < 2; ++cx) {
          const int ix = x0 + cx;
          const float wx = cx ? lx : 1.f - lx;
          const bool vx = (ix >= 0) && (ix < Wl);
          const int ixc = ix < 0 ? 0 : (ix > Wl - 1 ? Wl - 1 : ix);
          float g = (float)base[(size_t)(iyc * Wl + ixc) * 256];
          g = fminf(fmaxf(g, -BIGF), BIGF);  // NaN-guard only
          s += (vx && vy) ? wx * wy * g : 0.f;
        }
      }
      acc += wgt * s;
    }
  }
  accb[(size_t)row * 256 + t] = (bf16)acc;
}

extern "C" void kernel_launch(void* const* d_in, const int* in_sizes, int n_in,
                              void* d_out, int out_size, void* d_ws, size_t ws_size,
                              hipStream_t stream) {
  // dict order (harness-guaranteed)
  const void* query = d_in[0];
  const void* refp = d_in[1];
  const void* inpf = d_in[2];
  const void* W_off = d_in[5];
  const void* b_off = d_in[6];
  const void* W_attn = d_in[7];
  const void* b_attn = d_in[8];
  const void* W_val = d_in[9];
  const void* b_val = d_in[10];
  const void* W_out = d_in[11];
  const void* b_out = d_in[12];

  float* out = (float*)d_out;  // reference output dtype = float32
  char* ws = (char*)d_ws;
  int* flags = (int*)ws;
  const int* bf16flag = flags + 2;         // always 0
  bf16* Wt_val = (bf16*)(ws + 256);        // 131072 B
  bf16* Wt_out = (bf16*)(ws + 131328);     // 131072 B
  bf16* Wt_oa = (bf16*)(ws + 262400);      // 147456 B
  float* offs = (float*)(ws + 409856);     // 5529600 B
  float* logits = (float*)(ws + 5939456);  // 2764800 B
  bf16* accb = (bf16*)(ws + 8704256);      // 3686400 B
  bf16* value = (bf16*)(ws + 12390656);    // chunk 11010048 | full 88080384
  const unsigned long long WS_FULL = 12390656ULL + 88080384ULL;
  const unsigned long long WS_TIGHT = 12390656ULL + 11010048ULL;

  const int pipeline_ok = ws_size >= WS_TIGHT;
  const int full = ws_size >= WS_FULL;

  probe_flags<<<1, 64, 0, stream>>>((const bf16*)query, flags);
  if (pipeline_ok) {
    transpose_frag<<<256, 256, 0, stream>>>(W_val, Wt_val, flags);
    transpose_frag<<<256, 256, 0, stream>>>(W_out, Wt_out, flags);
    transpose_oa_frag<<<288, 256, 0, stream>>>(W_off, W_attn, Wt_oa, flags);
    gemm_oa_sf<<<(NROW + 63) / 64, 256, 0, stream>>>(query, Wt_oa, b_off, b_attn,
                                                     offs, logits, flags);
    if (full) {
      gemm_sf<bf16><<<(BSZ * SUMHW) / 64, 256, 0, stream>>>(
          inpf, Wt_val, b_val, value, 0, BSZ * SUMHW, flags, flags);
      msda_sample<<<dim3(NQ, BSZ), 256, 0, stream>>>(
          value, refp, offs, logits, accb, 0, (size_t)SUMHW * 256, flags);
    } else {
      for (int b = 0; b < BSZ; ++b) {
        gemm_sf<bf16><<<SUMHW / 64, 256, 0, stream>>>(
            inpf, Wt_val, b_val, value - (size_t)b * SUMHW * 256, b * SUMHW, SUMHW,
            flags, flags);
        msda_sample<<<dim3(NQ, 1), 256, 0, stream>>>(value, refp, offs, logits, accb,
                                                     b, 0, flags);
      }
    }
    gemm_sf<float><<<(NROW + 63) / 64, 256, 0, stream>>>(
        accb, Wt_out, b_out, out, 0, NROW, bf16flag, flags);
  }
}